// Round 1
// baseline (2528.362 us; speedup 1.0000x reference)
//
#include <hip/hip_runtime.h>
#include <hip/hip_bf16.h>

#define N_DIS   20000
#define DIM     128
#define EPS     1e-8f
#define LAMBDA  0.7f
#define TILE_E  32
#define SLICES  8
#define RPS     (N_DIS / SLICES)   // 2500 rows per slice

__device__ __forceinline__ bool beats(float v1, int i1, float v0, int i0) {
    return (v1 > v0) || (v1 == v0 && i1 < i0);
}

__device__ __forceinline__ void insert3(float v, int i,
                                        float& v0, int& i0,
                                        float& v1, int& i1,
                                        float& v2, int& i2) {
    if (beats(v, i, v0, i0)) { v2 = v1; i2 = i1; v1 = v0; i1 = i0; v0 = v; i0 = i; }
    else if (beats(v, i, v1, i1)) { v2 = v1; i2 = i1; v1 = v; i1 = i; }
    else if (beats(v, i, v2, i2)) { v2 = v; i2 = i; }
}

// ---------------- kernel 1: rnorm[r] = 1/(||h_disease[r]|| + eps) ----------------
__global__ __launch_bounds__(256) void k_rnorm(const float* __restrict__ hD,
                                               float* __restrict__ rnorm) {
    int t = blockIdx.x * 256 + threadIdx.x;
    int r = t >> 3;       // 8 threads per row
    int c = t & 7;
    if (r >= N_DIS) return;
    const float4* p = (const float4*)(hD + (size_t)r * DIM) + c * 4;
    float s = 0.f;
#pragma unroll
    for (int k = 0; k < 4; ++k) {
        float4 v = p[k];
        s += v.x * v.x + v.y * v.y + v.z * v.z + v.w * v.w;
    }
    s += __shfl_xor(s, 1);
    s += __shfl_xor(s, 2);
    s += __shfl_xor(s, 4);
    if (c == 0) rnorm[r] = 1.0f / (sqrtf(s) + EPS);
}

// ---------------- kernel 2: per-(edge, slice) top-3 of cosine sim ----------------
// grid = (E/TILE_E) * SLICES blocks, 256 threads.
// block handles TILE_E edges vs rows [slice*RPS, slice*RPS+RPS).
// thread (e = tid>>3, c = tid&7) scans rows  r0 + c + 8k.
__global__ __launch_bounds__(256) void k_simtop(const float* __restrict__ hD,
                                                const int* __restrict__ dst_dd,
                                                const float* __restrict__ rnorm,
                                                float* __restrict__ candV,
                                                int* __restrict__ candI,
                                                int E) {
    __shared__ float sdst[TILE_E][132];   // +4 pad: conflict-free b128 reads
    int tile  = blockIdx.x >> 3;
    int slice = blockIdx.x & 7;
    int tid = threadIdx.x;
    int e = tid >> 3, c = tid & 7;
    int eg = tile * TILE_E + e;
    int dst = dst_dd[min(eg, E - 1)];
    float rs = rnorm[dst];

    // stage normalized dst row into LDS
    const float4* pd = (const float4*)(hD + (size_t)dst * DIM) + c * 4;
#pragma unroll
    for (int k = 0; k < 4; ++k) {
        float4 v = pd[k];
        v.x *= rs; v.y *= rs; v.z *= rs; v.w *= rs;
        *(float4*)&sdst[e][c * 16 + k * 4] = v;
    }
    __syncthreads();

    int r0 = slice * RPS;
    int rend = r0 + RPS;
    float t0v = -INFINITY, t1v = -INFINITY, t2v = -INFINITY;
    int t0i = 0x7fffffff, t1i = 0x7fffffff, t2i = 0x7fffffff;

    for (int g = 0; g < 40; ++g) {          // 40*8 = 320 >= ceil(2500/8) rows/thread
        int rbase = r0 + c + 64 * g;        // rows rbase + 8j
        const float* pr[8];
        float rn[8];
#pragma unroll
        for (int j = 0; j < 8; ++j) {
            int ra = min(rbase + 8 * j, N_DIS - 1);
            pr[j] = hD + (size_t)ra * DIM;
            rn[j] = rnorm[ra];
        }
        float acc[8] = {0.f, 0.f, 0.f, 0.f, 0.f, 0.f, 0.f, 0.f};
#pragma unroll 4
        for (int chunk = 0; chunk < 32; ++chunk) {
            float4 dv = *(const float4*)&sdst[e][chunk * 4];
#pragma unroll
            for (int j = 0; j < 8; ++j) {
                float4 hv = *(const float4*)(pr[j] + chunk * 4);
                acc[j] = fmaf(dv.x, hv.x,
                         fmaf(dv.y, hv.y,
                         fmaf(dv.z, hv.z,
                         fmaf(dv.w, hv.w, acc[j]))));
            }
        }
#pragma unroll
        for (int j = 0; j < 8; ++j) {
            int r = rbase + 8 * j;
            float v = acc[j] * rn[j];
            if (r < rend && r != dst)
                insert3(v, r, t0v, t0i, t1v, t1i, t2v, t2i);
        }
    }

    // merge top-3 across the 8 threads of this edge (xor butterfly)
#pragma unroll
    for (int m = 1; m <= 4; m <<= 1) {
        float bv0 = __shfl_xor(t0v, m); int bi0 = __shfl_xor(t0i, m);
        float bv1 = __shfl_xor(t1v, m); int bi1 = __shfl_xor(t1i, m);
        float bv2 = __shfl_xor(t2v, m); int bi2 = __shfl_xor(t2i, m);
        insert3(bv0, bi0, t0v, t0i, t1v, t1i, t2v, t2i);
        insert3(bv1, bi1, t0v, t0i, t1v, t1i, t2v, t2i);
        insert3(bv2, bi2, t0v, t0i, t1v, t1i, t2v, t2i);
    }
    if (c == 0 && eg < E) {
        int base = eg * 24 + slice * 3;
        candV[base] = t0v; candV[base + 1] = t1v; candV[base + 2] = t2v;
        candI[base] = t0i; candI[base + 1] = t1i; candI[base + 2] = t2i;
    }
}

// ---------------- kernel 3: merge slices, softmax, prototype, score_dd ----------------
// one 64-lane wave per edge
__global__ __launch_bounds__(256) void k_dd_epilogue(const float* __restrict__ hDrug,
                                                     const float* __restrict__ hD,
                                                     const float* __restrict__ W,
                                                     const int* __restrict__ src_dd,
                                                     const int* __restrict__ dst_dd,
                                                     const int* __restrict__ deg,
                                                     const float* __restrict__ candV,
                                                     const int* __restrict__ candI,
                                                     float* __restrict__ out,
                                                     int E) {
    int wave = (blockIdx.x * 256 + threadIdx.x) >> 6;
    int lane = threadIdx.x & 63;
    if (wave >= E) return;
    int e = wave;
    int l8 = lane & 7;      // every 8-lane group mirrors the 8-slice merge
    int base = e * 24 + l8 * 3;
    float t0v = candV[base], t1v = candV[base + 1], t2v = candV[base + 2];
    int t0i = candI[base], t1i = candI[base + 1], t2i = candI[base + 2];
#pragma unroll
    for (int m = 1; m <= 4; m <<= 1) {
        float bv0 = __shfl_xor(t0v, m); int bi0 = __shfl_xor(t0i, m);
        float bv1 = __shfl_xor(t1v, m); int bi1 = __shfl_xor(t1i, m);
        float bv2 = __shfl_xor(t2v, m); int bi2 = __shfl_xor(t2i, m);
        insert3(bv0, bi0, t0v, t0i, t1v, t1i, t2v, t2i);
        insert3(bv1, bi1, t0v, t0i, t1v, t1i, t2v, t2i);
        insert3(bv2, bi2, t0v, t0i, t1v, t1i, t2v, t2i);
    }
    // softmax over (t0v >= t1v >= t2v)
    float w0 = 1.0f;
    float w1 = __expf(t1v - t0v);
    float w2 = __expf(t2v - t0v);
    // use precise expf to match reference closely
    w1 = expf(t1v - t0v);
    w2 = expf(t2v - t0v);
    float s = w0 + w1 + w2;
    w0 /= s; w1 /= s; w2 /= s;

    int dst = dst_dd[e], src = src_dd[e];
    float coef = expf(-LAMBDA * (float)deg[dst]);

    float2 a  = ((const float2*)(hD + (size_t)t0i * DIM))[lane];
    float2 b  = ((const float2*)(hD + (size_t)t1i * DIM))[lane];
    float2 cc = ((const float2*)(hD + (size_t)t2i * DIM))[lane];
    float2 de = ((const float2*)(hD + (size_t)dst * DIM))[lane];
    float2 se = ((const float2*)(hDrug + (size_t)src * DIM))[lane];
    float2 wv = ((const float2*)W)[lane];            // W[0]

    float px = w0 * a.x + w1 * b.x + w2 * cc.x;
    float py = w0 * a.y + w1 * b.y + w2 * cc.y;
    float ax = (1.0f - coef) * de.x + coef * px;
    float ay = (1.0f - coef) * de.y + coef * py;
    float t = se.x * wv.x * ax + se.y * wv.y * ay;
#pragma unroll
    for (int m = 1; m <= 32; m <<= 1) t += __shfl_xor(t, m);
    if (lane == 0) out[e] = t;
}

// ---------------- kernel 4: score_nn, 8 lanes per edge ----------------
__global__ __launch_bounds__(256) void k_nn(const float* __restrict__ hD,
                                            const float* __restrict__ W,
                                            const int* __restrict__ src_nn,
                                            const int* __restrict__ dst_nn,
                                            float* __restrict__ out,
                                            int E) {
    int c = threadIdx.x & 7;
    const float4* W1 = (const float4*)(W + DIM) + c * 4;
    float4 w[4];
#pragma unroll
    for (int k = 0; k < 4; ++k) w[k] = W1[k];

    for (int e = (blockIdx.x * 256 + threadIdx.x) >> 3; e < E; e += gridDim.x * 32) {
        int s = src_nn[e], d = dst_nn[e];
        const float4* ps = (const float4*)(hD + (size_t)s * DIM) + c * 4;
        const float4* pd = (const float4*)(hD + (size_t)d * DIM) + c * 4;
        float acc = 0.f;
#pragma unroll
        for (int k = 0; k < 4; ++k) {
            float4 a = ps[k], b = pd[k];
            acc = fmaf(a.x * w[k].x, b.x, acc);
            acc = fmaf(a.y * w[k].y, b.y, acc);
            acc = fmaf(a.z * w[k].z, b.z, acc);
            acc = fmaf(a.w * w[k].w, b.w, acc);
        }
        acc += __shfl_xor(acc, 1);
        acc += __shfl_xor(acc, 2);
        acc += __shfl_xor(acc, 4);
        if (c == 0) out[e] = acc;
    }
}

extern "C" void kernel_launch(void* const* d_in, const int* in_sizes, int n_in,
                              void* d_out, int out_size, void* d_ws, size_t ws_size,
                              hipStream_t stream) {
    const float* h_drug = (const float*)d_in[0];
    const float* h_dis  = (const float*)d_in[1];
    const float* W      = (const float*)d_in[2];
    const int* src_dd   = (const int*)d_in[3];
    const int* dst_dd   = (const int*)d_in[4];
    const int* src_nn   = (const int*)d_in[5];
    const int* dst_nn   = (const int*)d_in[6];
    const int* deg      = (const int*)d_in[7];
    int E_DD = in_sizes[3];
    int E_NN = in_sizes[5];
    float* out = (float*)d_out;

    float* rnorm = (float*)d_ws;                    // 20000 f32
    float* candV = rnorm + N_DIS;                   // E_DD*24 f32
    int*   candI = (int*)(candV + (size_t)E_DD * 24);

    k_rnorm<<<(N_DIS * 8 + 255) / 256, 256, 0, stream>>>(h_dis, rnorm);

    int tiles = (E_DD + TILE_E - 1) / TILE_E;
    k_simtop<<<tiles * SLICES, 256, 0, stream>>>(h_dis, dst_dd, rnorm, candV, candI, E_DD);

    k_dd_epilogue<<<(E_DD + 3) / 4, 256, 0, stream>>>(h_drug, h_dis, W, src_dd, dst_dd,
                                                      deg, candV, candI, out, E_DD);

    k_nn<<<2048, 256, 0, stream>>>(h_dis, W, src_nn, dst_nn, out + E_DD, E_NN);
}

// Round 6
// 697.603 us; speedup vs baseline: 3.6244x; 3.6244x over previous
//
#include <hip/hip_runtime.h>
#include <hip/hip_bf16.h>

#define N_DIS   20000
#define DIM     128
#define EPS     1e-8f
#define LAMBDA  0.7f

#define KC      32          // K chunk
#define NT      256         // rows per tile
#define ETILE   64          // edges per block
#define RTILES  ((N_DIS + NT - 1) / NT)       // 79
#define RT_G    2           // row-tiles per block
#define RTG     ((RTILES + RT_G - 1) / RT_G)  // 40
#define CPAD    (RTG * 3)   // candidate stride per edge (120)

__device__ __forceinline__ bool beats(float v1, int i1, float v0, int i0) {
    return (v1 > v0) || (v1 == v0 && i1 < i0);
}

__device__ __forceinline__ void insert3(float v, int i,
                                        float& v0, int& i0,
                                        float& v1, int& i1,
                                        float& v2, int& i2) {
    if (beats(v, i, v0, i0)) { v2 = v1; i2 = i1; v1 = v0; i1 = i0; v0 = v; i0 = i; }
    else if (beats(v, i, v1, i1)) { v2 = v1; i2 = i1; v1 = v; i1 = i; }
    else if (beats(v, i, v2, i2)) { v2 = v; i2 = i; }
}

// ---------------- kernel 1: rnorm[r] = 1/(||h_disease[r]|| + eps) ----------------
__global__ __launch_bounds__(256) void k_rnorm(const float* __restrict__ hD,
                                               float* __restrict__ rnorm) {
    int t = blockIdx.x * 256 + threadIdx.x;
    int r = t >> 3;
    int c = t & 7;
    if (r >= N_DIS) return;
    const float4* p = (const float4*)(hD + (size_t)r * DIM) + c * 4;
    float s = 0.f;
#pragma unroll
    for (int k = 0; k < 4; ++k) {
        float4 v = p[k];
        s += v.x * v.x + v.y * v.y + v.z * v.z + v.w * v.w;
    }
    s += __shfl_xor(s, 1);
    s += __shfl_xor(s, 2);
    s += __shfl_xor(s, 4);
    if (c == 0) rnorm[r] = 1.0f / (sqrtf(s) + EPS);
}

// ---------------- kernel 2: LDS-tiled sim GEMM + fused top-3 ----------------
// block: 64 edges x (RT_G row-tiles of 256 rows), K chunked by 32.
// thread (ty=tid>>5, tx=tid&31): 8 edges (ty*8..) x 8 rows ({4tx..4tx+3} u {128+4tx..}).
__global__ __launch_bounds__(256, 3) void k_simtop(const float* __restrict__ hD,
                                                   const int* __restrict__ dst_dd,
                                                   const float* __restrict__ rnorm,
                                                   float* __restrict__ candV,
                                                   int* __restrict__ candI,
                                                   int E, int ET) {
    __shared__ float sA[KC][68];    // edges, k-major (+pad: 2-way max on r/w)
    __shared__ float sB[KC][260];   // rows,  k-major (reads at 512B/wave LDS floor)

    // XCD-contiguous swizzle: consecutive g on one XCD -> contiguous row-tile groups
    int L = blockIdx.x, G = gridDim.x;
    int g = (G % 8 == 0) ? ((L & 7) * (G >> 3) + (L >> 3)) : L;
    int rtg = g / ET;
    int et  = g % ET;
    int e0  = et * ETILE;
    int tid = threadIdx.x;
    int ty = tid >> 5, tx = tid & 31;

    // sA staging role: edge sa_e = tid>>2, quad sa_q = tid&3 (block-constant)
    int sa_e = tid >> 2, sa_q = tid & 3;
    int sa_edge = min(e0 + sa_e, E - 1);
    int sa_dst = dst_dd[sa_edge];
    float sa_rn = rnorm[sa_dst];
    const float* sa_src = hD + (size_t)sa_dst * DIM;

    // this thread's 8 edges (for self-masking)
    int dste[8];
#pragma unroll
    for (int i = 0; i < 8; ++i) dste[i] = dst_dd[min(e0 + ty * 8 + i, E - 1)];

    float t0v[8], t1v[8], t2v[8];
    int   t0i[8], t1i[8], t2i[8];
#pragma unroll
    for (int i = 0; i < 8; ++i) {
        t0v[i] = -INFINITY; t1v[i] = -INFINITY; t2v[i] = -INFINITY;
        t0i[i] = 0x7fffffff; t1i[i] = 0x7fffffff; t2i[i] = 0x7fffffff;
    }

    for (int tt = 0; tt < RT_G; ++tt) {
        int rt = rtg * RT_G + tt;
        if (rt >= RTILES) break;            // uniform across block
        int rb = rt * NT;

        int sb_r = min(rb + tid, N_DIS - 1);
        float sb_rn = rnorm[sb_r];
        const float* sb_src = hD + (size_t)sb_r * DIM;

        float acc[8][8];
#pragma unroll
        for (int e = 0; e < 8; ++e)
#pragma unroll
            for (int j = 0; j < 8; ++j) acc[e][j] = 0.f;

        for (int c = 0; c < DIM / KC; ++c) {
            int kc0 = c * KC;
            __syncthreads();                 // protect previous chunk's reads
            // stage sA chunk: 2 float4 per thread, normalized
#pragma unroll
            for (int h = 0; h < 2; ++h) {
                int f = sa_q + h * 4;
                float4 v = *(const float4*)(sa_src + kc0 + f * 4);
                sA[f * 4 + 0][sa_e] = v.x * sa_rn;
                sA[f * 4 + 1][sa_e] = v.y * sa_rn;
                sA[f * 4 + 2][sa_e] = v.z * sa_rn;
                sA[f * 4 + 3][sa_e] = v.w * sa_rn;
            }
            // stage sB chunk: thread stages its row's 32 k's, normalized
#pragma unroll
            for (int f = 0; f < 8; ++f) {
                float4 v = *(const float4*)(sb_src + kc0 + f * 4);
                sB[f * 4 + 0][tid] = v.x * sb_rn;
                sB[f * 4 + 1][tid] = v.y * sb_rn;
                sB[f * 4 + 2][tid] = v.z * sb_rn;
                sB[f * 4 + 3][tid] = v.w * sb_rn;
            }
            __syncthreads();
#pragma unroll 4
            for (int kl = 0; kl < KC; ++kl) {
                float4 ea = *(const float4*)&sA[kl][ty * 8];
                float4 eb = *(const float4*)&sA[kl][ty * 8 + 4];
                float4 ra = *(const float4*)&sB[kl][tx * 4];
                float4 rc = *(const float4*)&sB[kl][tx * 4 + 128];
                float ev[8] = {ea.x, ea.y, ea.z, ea.w, eb.x, eb.y, eb.z, eb.w};
                float rv[8] = {ra.x, ra.y, ra.z, ra.w, rc.x, rc.y, rc.z, rc.w};
#pragma unroll
                for (int e = 0; e < 8; ++e)
#pragma unroll
                    for (int j = 0; j < 8; ++j)
                        acc[e][j] = fmaf(ev[e], rv[j], acc[e][j]);
            }
        }

        // fused top-3 insert for this tile (filter by tile max vs current 3rd)
#pragma unroll
        for (int e = 0; e < 8; ++e) {
            float m = acc[e][0];
#pragma unroll
            for (int j = 1; j < 8; ++j) m = fmaxf(m, acc[e][j]);
            if (m > t2v[e]) {
#pragma unroll
                for (int j = 0; j < 8; ++j) {
                    int r = rb + tx * 4 + (j & 3) + ((j >> 2) << 7);
                    bool ok = (r < N_DIS) && (r != dste[e]);
                    insert3(ok ? acc[e][j] : -INFINITY, r,
                            t0v[e], t0i[e], t1v[e], t1i[e], t2v[e], t2i[e]);
                }
            }
        }
    }

    // merge across the 32 tx lanes of each ty group (xor butterfly)
#pragma unroll
    for (int m = 1; m <= 16; m <<= 1) {
#pragma unroll
        for (int e = 0; e < 8; ++e) {
            float bv0 = __shfl_xor(t0v[e], m); int bi0 = __shfl_xor(t0i[e], m);
            float bv1 = __shfl_xor(t1v[e], m); int bi1 = __shfl_xor(t1i[e], m);
            float bv2 = __shfl_xor(t2v[e], m); int bi2 = __shfl_xor(t2i[e], m);
            insert3(bv0, bi0, t0v[e], t0i[e], t1v[e], t1i[e], t2v[e], t2i[e]);
            insert3(bv1, bi1, t0v[e], t0i[e], t1v[e], t1i[e], t2v[e], t2i[e]);
            insert3(bv2, bi2, t0v[e], t0i[e], t1v[e], t1i[e], t2v[e], t2i[e]);
        }
    }
    if (tx == 0) {
#pragma unroll
        for (int e = 0; e < 8; ++e) {
            int eg = e0 + ty * 8 + e;
            if (eg < E) {
                size_t base = (size_t)eg * CPAD + rtg * 3;
                candV[base + 0] = t0v[e]; candV[base + 1] = t1v[e]; candV[base + 2] = t2v[e];
                candI[base + 0] = t0i[e]; candI[base + 1] = t1i[e]; candI[base + 2] = t2i[e];
            }
        }
    }
}

// ---------------- kernel 3: merge candidates, softmax, prototype, score_dd ----------------
// one 64-lane wave per edge
__global__ __launch_bounds__(256) void k_dd_epilogue(const float* __restrict__ hDrug,
                                                     const float* __restrict__ hD,
                                                     const float* __restrict__ W,
                                                     const int* __restrict__ src_dd,
                                                     const int* __restrict__ dst_dd,
                                                     const int* __restrict__ deg,
                                                     const float* __restrict__ candV,
                                                     const int* __restrict__ candI,
                                                     float* __restrict__ out,
                                                     int E) {
    int wave = (blockIdx.x * 256 + threadIdx.x) >> 6;
    int lane = threadIdx.x & 63;
    if (wave >= E) return;
    int e = wave;

    float v0 = -INFINITY, v1 = -INFINITY, v2 = -INFINITY;
    int i0 = 0x7fffffff, i1 = 0x7fffffff, i2 = 0x7fffffff;
    for (int p = lane; p < CPAD; p += 64) {
        float v = candV[(size_t)e * CPAD + p];
        int   i = candI[(size_t)e * CPAD + p];
        insert3(v, i, v0, i0, v1, i1, v2, i2);
    }
#pragma unroll
    for (int m = 1; m <= 32; m <<= 1) {
        float bv0 = __shfl_xor(v0, m); int bi0 = __shfl_xor(i0, m);
        float bv1 = __shfl_xor(v1, m); int bi1 = __shfl_xor(i1, m);
        float bv2 = __shfl_xor(v2, m); int bi2 = __shfl_xor(i2, m);
        insert3(bv0, bi0, v0, i0, v1, i1, v2, i2);
        insert3(bv1, bi1, v0, i0, v1, i1, v2, i2);
        insert3(bv2, bi2, v0, i0, v1, i1, v2, i2);
    }

    float w1 = expf(v1 - v0);
    float w2 = expf(v2 - v0);
    float s = 1.0f + w1 + w2;
    float w0 = 1.0f / s;
    w1 /= s; w2 /= s;

    int dst = dst_dd[e], src = src_dd[e];
    float coef = expf(-LAMBDA * (float)deg[dst]);

    float2 a  = ((const float2*)(hD + (size_t)i0 * DIM))[lane];
    float2 b  = ((const float2*)(hD + (size_t)i1 * DIM))[lane];
    float2 cc = ((const float2*)(hD + (size_t)i2 * DIM))[lane];
    float2 de = ((const float2*)(hD + (size_t)dst * DIM))[lane];
    float2 se = ((const float2*)(hDrug + (size_t)src * DIM))[lane];
    float2 wv = ((const float2*)W)[lane];            // W[0]

    float px = w0 * a.x + w1 * b.x + w2 * cc.x;
    float py = w0 * a.y + w1 * b.y + w2 * cc.y;
    float ax = (1.0f - coef) * de.x + coef * px;
    float ay = (1.0f - coef) * de.y + coef * py;
    float t = se.x * wv.x * ax + se.y * wv.y * ay;
#pragma unroll
    for (int m = 1; m <= 32; m <<= 1) t += __shfl_xor(t, m);
    if (lane == 0) out[e] = t;
}

// ---------------- kernel 4: score_nn, 8 lanes per edge ----------------
__global__ __launch_bounds__(256) void k_nn(const float* __restrict__ hD,
                                            const float* __restrict__ W,
                                            const int* __restrict__ src_nn,
                                            const int* __restrict__ dst_nn,
                                            float* __restrict__ out,
                                            int E) {
    int c = threadIdx.x & 7;
    const float4* W1 = (const float4*)(W + DIM) + c * 4;
    float4 w[4];
#pragma unroll
    for (int k = 0; k < 4; ++k) w[k] = W1[k];

    for (int e = (blockIdx.x * 256 + threadIdx.x) >> 3; e < E; e += gridDim.x * 32) {
        int s = src_nn[e], d = dst_nn[e];
        const float4* ps = (const float4*)(hD + (size_t)s * DIM) + c * 4;
        const float4* pd = (const float4*)(hD + (size_t)d * DIM) + c * 4;
        float acc = 0.f;
#pragma unroll
        for (int k = 0; k < 4; ++k) {
            float4 a = ps[k], b = pd[k];
            acc = fmaf(a.x * w[k].x, b.x, acc);
            acc = fmaf(a.y * w[k].y, b.y, acc);
            acc = fmaf(a.z * w[k].z, b.z, acc);
            acc = fmaf(a.w * w[k].w, b.w, acc);
        }
        acc += __shfl_xor(acc, 1);
        acc += __shfl_xor(acc, 2);
        acc += __shfl_xor(acc, 4);
        if (c == 0) out[e] = acc;
    }
}

extern "C" void kernel_launch(void* const* d_in, const int* in_sizes, int n_in,
                              void* d_out, int out_size, void* d_ws, size_t ws_size,
                              hipStream_t stream) {
    const float* h_drug = (const float*)d_in[0];
    const float* h_dis  = (const float*)d_in[1];
    const float* W      = (const float*)d_in[2];
    const int* src_dd   = (const int*)d_in[3];
    const int* dst_dd   = (const int*)d_in[4];
    const int* src_nn   = (const int*)d_in[5];
    const int* dst_nn   = (const int*)d_in[6];
    const int* deg      = (const int*)d_in[7];
    int E_DD = in_sizes[3];
    int E_NN = in_sizes[5];
    float* out = (float*)d_out;

    float* rnorm = (float*)d_ws;                         // 20000 f32
    float* candV = rnorm + N_DIS;                        // E_DD*CPAD f32
    int*   candI = (int*)(candV + (size_t)E_DD * CPAD);  // E_DD*CPAD i32

    k_rnorm<<<(N_DIS * 8 + 255) / 256, 256, 0, stream>>>(h_dis, rnorm);

    int ET = (E_DD + ETILE - 1) / ETILE;                 // 32 edge-tiles
    k_simtop<<<ET * RTG, 256, 0, stream>>>(h_dis, dst_dd, rnorm, candV, candI, E_DD, ET);

    k_dd_epilogue<<<(E_DD + 3) / 4, 256, 0, stream>>>(h_drug, h_dis, W, src_dd, dst_dd,
                                                      deg, candV, candI, out, E_DD);

    k_nn<<<2048, 256, 0, stream>>>(h_dis, W, src_nn, dst_nn, out + E_DD, E_NN);
}

// Round 8
// 662.970 us; speedup vs baseline: 3.8137x; 1.0522x over previous
//
#include <hip/hip_runtime.h>
#include <hip/hip_bf16.h>

#define N_DIS   20000
#define DIM     128
#define EPS     1e-8f
#define LAMBDA  0.7f

#define KC      32          // K chunk
#define NT      256         // rows per tile
#define ETILE   32          // edges per block (8 ty-groups x 4 edges)
#define RTILES  ((N_DIS + NT - 1) / NT)       // 79
#define RT_G    2           // row-tiles per block
#define RTG     ((RTILES + RT_G - 1) / RT_G)  // 40
#define CPAD    (RTG * 3)   // candidate stride per edge (120)

__device__ __forceinline__ bool beats(float v1, int i1, float v0, int i0) {
    return (v1 > v0) || (v1 == v0 && i1 < i0);
}

__device__ __forceinline__ void insert3(float v, int i,
                                        float& v0, int& i0,
                                        float& v1, int& i1,
                                        float& v2, int& i2) {
    if (beats(v, i, v0, i0)) { v2 = v1; i2 = i1; v1 = v0; i1 = i0; v0 = v; i0 = i; }
    else if (beats(v, i, v1, i1)) { v2 = v1; i2 = i1; v1 = v; i1 = i; }
    else if (beats(v, i, v2, i2)) { v2 = v; i2 = i; }
}

// ---------------- kernel 1: rnorm[r] = 1/(||h_disease[r]|| + eps) ----------------
__global__ __launch_bounds__(256) void k_rnorm(const float* __restrict__ hD,
                                               float* __restrict__ rnorm) {
    int t = blockIdx.x * 256 + threadIdx.x;
    int r = t >> 3;
    int c = t & 7;
    if (r >= N_DIS) return;
    const float4* p = (const float4*)(hD + (size_t)r * DIM) + c * 4;
    float s = 0.f;
#pragma unroll
    for (int k = 0; k < 4; ++k) {
        float4 v = p[k];
        s += v.x * v.x + v.y * v.y + v.z * v.z + v.w * v.w;
    }
    s += __shfl_xor(s, 1);
    s += __shfl_xor(s, 2);
    s += __shfl_xor(s, 4);
    if (c == 0) rnorm[r] = 1.0f / (sqrtf(s) + EPS);
}

// ---------------- kernel 2: LDS-tiled sim GEMM + fused top-3 (spill-free sizing) ----
// block: 32 edges x (RT_G row-tiles of 256 rows), K chunked by 32.
// thread (ty=tid>>5, tx=tid&31): 4 edges (ty*4..) x 8 rows ({4tx..4tx+3} u {128+4tx..}).
// Register budget: 32 acc + 24 top3 + 4 dste + ~40 addr/temps ~= 100-110 -> fits (256,4)=128.
__global__ __launch_bounds__(256, 4) void k_simtop(const float* __restrict__ hD,
                                                   const int* __restrict__ dst_dd,
                                                   const float* __restrict__ rnorm,
                                                   float* __restrict__ candV,
                                                   int* __restrict__ candI,
                                                   int E, int ET) {
    __shared__ float sA[KC][36];    // 32 edges, k-major (+4 pad)
    __shared__ float sB[KC][260];   // 256 rows, k-major (+4 pad)

    // XCD-contiguous swizzle: consecutive g on one XCD -> contiguous row-tile groups
    int L = blockIdx.x, G = gridDim.x;
    int g = (G % 8 == 0) ? ((L & 7) * (G >> 3) + (L >> 3)) : L;
    int rtg = g / ET;
    int et  = g % ET;
    int e0  = et * ETILE;
    int tid = threadIdx.x;
    int ty = tid >> 5, tx = tid & 31;

    // sA staging role: edge sa_e = tid>>3 (0..31), float4-slot sa_q = tid&7
    int sa_e = tid >> 3, sa_q = tid & 7;
    int sa_edge = min(e0 + sa_e, E - 1);
    int sa_dst = dst_dd[sa_edge];
    float sa_rn = rnorm[sa_dst];
    const float* sa_src = hD + (size_t)sa_dst * DIM;

    // this thread's 4 edges (for self-masking)
    int dste[4];
#pragma unroll
    for (int i = 0; i < 4; ++i) dste[i] = dst_dd[min(e0 + ty * 4 + i, E - 1)];

    float t0v[4], t1v[4], t2v[4];
    int   t0i[4], t1i[4], t2i[4];
#pragma unroll
    for (int i = 0; i < 4; ++i) {
        t0v[i] = -INFINITY; t1v[i] = -INFINITY; t2v[i] = -INFINITY;
        t0i[i] = 0x7fffffff; t1i[i] = 0x7fffffff; t2i[i] = 0x7fffffff;
    }

    for (int tt = 0; tt < RT_G; ++tt) {
        int rt = rtg * RT_G + tt;
        if (rt >= RTILES) break;            // uniform across block
        int rb = rt * NT;

        int sb_r = min(rb + tid, N_DIS - 1);
        float sb_rn = rnorm[sb_r];
        const float* sb_src = hD + (size_t)sb_r * DIM;

        float acc[4][8];
#pragma unroll
        for (int e = 0; e < 4; ++e)
#pragma unroll
            for (int j = 0; j < 8; ++j) acc[e][j] = 0.f;

        for (int c = 0; c < DIM / KC; ++c) {
            int kc0 = c * KC;
            __syncthreads();                 // protect previous chunk's reads
            // stage sA chunk: 1 float4 per thread, normalized
            {
                float4 v = *(const float4*)(sa_src + kc0 + sa_q * 4);
                sA[sa_q * 4 + 0][sa_e] = v.x * sa_rn;
                sA[sa_q * 4 + 1][sa_e] = v.y * sa_rn;
                sA[sa_q * 4 + 2][sa_e] = v.z * sa_rn;
                sA[sa_q * 4 + 3][sa_e] = v.w * sa_rn;
            }
            // stage sB chunk: thread stages its row's 32 k's, normalized
#pragma unroll
            for (int f = 0; f < 8; ++f) {
                float4 v = *(const float4*)(sb_src + kc0 + f * 4);
                sB[f * 4 + 0][tid] = v.x * sb_rn;
                sB[f * 4 + 1][tid] = v.y * sb_rn;
                sB[f * 4 + 2][tid] = v.z * sb_rn;
                sB[f * 4 + 3][tid] = v.w * sb_rn;
            }
            __syncthreads();
#pragma unroll 2
            for (int kl = 0; kl < KC; ++kl) {
                float4 ea = *(const float4*)&sA[kl][ty * 4];
                float4 ra = *(const float4*)&sB[kl][tx * 4];
                float4 rc = *(const float4*)&sB[kl][tx * 4 + 128];
                float ev[4] = {ea.x, ea.y, ea.z, ea.w};
                float rv[8] = {ra.x, ra.y, ra.z, ra.w, rc.x, rc.y, rc.z, rc.w};
#pragma unroll
                for (int e = 0; e < 4; ++e)
#pragma unroll
                    for (int j = 0; j < 8; ++j)
                        acc[e][j] = fmaf(ev[e], rv[j], acc[e][j]);
            }
        }

        // fused top-3 insert for this tile (filter by tile max vs current 3rd)
#pragma unroll
        for (int e = 0; e < 4; ++e) {
            float m = acc[e][0];
#pragma unroll
            for (int j = 1; j < 8; ++j) m = fmaxf(m, acc[e][j]);
            if (m > t2v[e]) {
#pragma unroll
                for (int j = 0; j < 8; ++j) {
                    int r = rb + tx * 4 + (j & 3) + ((j >> 2) << 7);
                    bool ok = (r < N_DIS) && (r != dste[e]);
                    insert3(ok ? acc[e][j] : -INFINITY, r,
                            t0v[e], t0i[e], t1v[e], t1i[e], t2v[e], t2i[e]);
                }
            }
        }
    }

    // merge across the 32 tx lanes of each ty group (xor butterfly)
#pragma unroll
    for (int m = 1; m <= 16; m <<= 1) {
#pragma unroll
        for (int e = 0; e < 4; ++e) {
            float bv0 = __shfl_xor(t0v[e], m); int bi0 = __shfl_xor(t0i[e], m);
            float bv1 = __shfl_xor(t1v[e], m); int bi1 = __shfl_xor(t1i[e], m);
            float bv2 = __shfl_xor(t2v[e], m); int bi2 = __shfl_xor(t2i[e], m);
            insert3(bv0, bi0, t0v[e], t0i[e], t1v[e], t1i[e], t2v[e], t2i[e]);
            insert3(bv1, bi1, t0v[e], t0i[e], t1v[e], t1i[e], t2v[e], t2i[e]);
            insert3(bv2, bi2, t0v[e], t0i[e], t1v[e], t1i[e], t2v[e], t2i[e]);
        }
    }
    if (tx == 0) {
#pragma unroll
        for (int e = 0; e < 4; ++e) {
            int eg = e0 + ty * 4 + e;
            if (eg < E) {
                size_t base = (size_t)eg * CPAD + rtg * 3;
                candV[base + 0] = t0v[e]; candV[base + 1] = t1v[e]; candV[base + 2] = t2v[e];
                candI[base + 0] = t0i[e]; candI[base + 1] = t1i[e]; candI[base + 2] = t2i[e];
            }
        }
    }
}

// ---------------- kernel 3: merge candidates, softmax, prototype, score_dd ----------------
// one 64-lane wave per edge
__global__ __launch_bounds__(256) void k_dd_epilogue(const float* __restrict__ hDrug,
                                                     const float* __restrict__ hD,
                                                     const float* __restrict__ W,
                                                     const int* __restrict__ src_dd,
                                                     const int* __restrict__ dst_dd,
                                                     const int* __restrict__ deg,
                                                     const float* __restrict__ candV,
                                                     const int* __restrict__ candI,
                                                     float* __restrict__ out,
                                                     int E) {
    int wave = (blockIdx.x * 256 + threadIdx.x) >> 6;
    int lane = threadIdx.x & 63;
    if (wave >= E) return;
    int e = wave;

    float v0 = -INFINITY, v1 = -INFINITY, v2 = -INFINITY;
    int i0 = 0x7fffffff, i1 = 0x7fffffff, i2 = 0x7fffffff;
    for (int p = lane; p < CPAD; p += 64) {
        float v = candV[(size_t)e * CPAD + p];
        int   i = candI[(size_t)e * CPAD + p];
        insert3(v, i, v0, i0, v1, i1, v2, i2);
    }
#pragma unroll
    for (int m = 1; m <= 32; m <<= 1) {
        float bv0 = __shfl_xor(v0, m); int bi0 = __shfl_xor(i0, m);
        float bv1 = __shfl_xor(v1, m); int bi1 = __shfl_xor(i1, m);
        float bv2 = __shfl_xor(v2, m); int bi2 = __shfl_xor(i2, m);
        insert3(bv0, bi0, v0, i0, v1, i1, v2, i2);
        insert3(bv1, bi1, v0, i0, v1, i1, v2, i2);
        insert3(bv2, bi2, v0, i0, v1, i1, v2, i2);
    }

    float w1 = expf(v1 - v0);
    float w2 = expf(v2 - v0);
    float s = 1.0f + w1 + w2;
    float w0 = 1.0f / s;
    w1 /= s; w2 /= s;

    int dst = dst_dd[e], src = src_dd[e];
    float coef = expf(-LAMBDA * (float)deg[dst]);

    float2 a  = ((const float2*)(hD + (size_t)i0 * DIM))[lane];
    float2 b  = ((const float2*)(hD + (size_t)i1 * DIM))[lane];
    float2 cc = ((const float2*)(hD + (size_t)i2 * DIM))[lane];
    float2 de = ((const float2*)(hD + (size_t)dst * DIM))[lane];
    float2 se = ((const float2*)(hDrug + (size_t)src * DIM))[lane];
    float2 wv = ((const float2*)W)[lane];            // W[0]

    float px = w0 * a.x + w1 * b.x + w2 * cc.x;
    float py = w0 * a.y + w1 * b.y + w2 * cc.y;
    float ax = (1.0f - coef) * de.x + coef * px;
    float ay = (1.0f - coef) * de.y + coef * py;
    float t = se.x * wv.x * ax + se.y * wv.y * ay;
#pragma unroll
    for (int m = 1; m <= 32; m <<= 1) t += __shfl_xor(t, m);
    if (lane == 0) out[e] = t;
}

// ---------------- kernel 4: score_nn, 8 lanes per edge ----------------
__global__ __launch_bounds__(256) void k_nn(const float* __restrict__ hD,
                                            const float* __restrict__ W,
                                            const int* __restrict__ src_nn,
                                            const int* __restrict__ dst_nn,
                                            float* __restrict__ out,
                                            int E) {
    int c = threadIdx.x & 7;
    const float4* W1 = (const float4*)(W + DIM) + c * 4;
    float4 w[4];
#pragma unroll
    for (int k = 0; k < 4; ++k) w[k] = W1[k];

    for (int e = (blockIdx.x * 256 + threadIdx.x) >> 3; e < E; e += gridDim.x * 32) {
        int s = src_nn[e], d = dst_nn[e];
        const float4* ps = (const float4*)(hD + (size_t)s * DIM) + c * 4;
        const float4* pd = (const float4*)(hD + (size_t)d * DIM) + c * 4;
        float acc = 0.f;
#pragma unroll
        for (int k = 0; k < 4; ++k) {
            float4 a = ps[k], b = pd[k];
            acc = fmaf(a.x * w[k].x, b.x, acc);
            acc = fmaf(a.y * w[k].y, b.y, acc);
            acc = fmaf(a.z * w[k].z, b.z, acc);
            acc = fmaf(a.w * w[k].w, b.w, acc);
        }
        acc += __shfl_xor(acc, 1);
        acc += __shfl_xor(acc, 2);
        acc += __shfl_xor(acc, 4);
        if (c == 0) out[e] = acc;
    }
}

extern "C" void kernel_launch(void* const* d_in, const int* in_sizes, int n_in,
                              void* d_out, int out_size, void* d_ws, size_t ws_size,
                              hipStream_t stream) {
    const float* h_drug = (const float*)d_in[0];
    const float* h_dis  = (const float*)d_in[1];
    const float* W      = (const float*)d_in[2];
    const int* src_dd   = (const int*)d_in[3];
    const int* dst_dd   = (const int*)d_in[4];
    const int* src_nn   = (const int*)d_in[5];
    const int* dst_nn   = (const int*)d_in[6];
    const int* deg      = (const int*)d_in[7];
    int E_DD = in_sizes[3];
    int E_NN = in_sizes[5];
    float* out = (float*)d_out;

    float* rnorm = (float*)d_ws;                         // 20000 f32
    float* candV = rnorm + N_DIS;                        // E_DD*CPAD f32
    int*   candI = (int*)(candV + (size_t)E_DD * CPAD);  // E_DD*CPAD i32

    k_rnorm<<<(N_DIS * 8 + 255) / 256, 256, 0, stream>>>(h_dis, rnorm);

    int ET = (E_DD + ETILE - 1) / ETILE;                 // 64 edge-tiles
    k_simtop<<<ET * RTG, 256, 0, stream>>>(h_dis, dst_dd, rnorm, candV, candI, E_DD, ET);

    k_dd_epilogue<<<(E_DD + 3) / 4, 256, 0, stream>>>(h_drug, h_dis, W, src_dd, dst_dd,
                                                      deg, candV, candI, out, E_DD);

    k_nn<<<2048, 256, 0, stream>>>(h_dis, W, src_nn, dst_nn, out + E_DD, E_NN);
}